// Round 16
// baseline (89.027 us; speedup 1.0000x reference)
//
#include <hip/hip_runtime.h>

// VecLocal2d R16 = R15 theory (staged-A + 2 blocks/CU) with the FPAD
// capacity bug fixed by resizing the block: (pixel, bk-fifth of 32 rows),
// grid 5120, 256 thr (4 waves = 4 nt, mt in {0,1}).
// LDS = A 9 planes x 32 rows (18432 B) + W[64][292] bf16 (37376 B)
//     = 55808 B -> 2 blocks/CU (the untested occupancy+staged-A combo).
// FPAD2=292 >= 288 (R15's bug: 280 rows overflowed into each other).
// W re-read 5x/pixel: all 5 slices of a pixel share an XCD (hb&7=xcd,
// slices contiguous) so re-reads are L2-hits. A is not duplicated.
// hz/t1(pre-swizzled)/t2/R3-fallback verbatim from R9 (passed, 0.03125).

#define HW    32
#define CIN   32
#define COUT  64
#define FDIM  288
#define FPAD  296              // R3-fallback W pad
#define NBK   160
#define HP    34
#define PLANE 5120             // full xc plane shorts (160 bk x 32 c)
#define SPL   1024             // per-slice plane shorts (32 bk x 32 c)
#define WOFF3 (9 * SPL)        // 9216 shorts: W region start
#define FPAD2 292              // >=288; 584B rows -> 18 dw mod 32, <=2-way

using f32x4  = __attribute__((ext_vector_type(4))) float;
using bf16x8 = __attribute__((ext_vector_type(8))) short;
using s16x4  = __attribute__((ext_vector_type(4))) short;

static __device__ inline unsigned short f2bf(float f) {
    unsigned u = __float_as_uint(f);
    u += 0x7FFFu + ((u >> 16) & 1u);   // round-to-nearest-even
    return (unsigned short)(u >> 16);
}
static __device__ inline float bf2f(short h) {
    return __uint_as_float(((unsigned)(unsigned short)h) << 16);
}
static __device__ inline void gl_lds16(const short* src, short* dst) {
    __builtin_amdgcn_global_load_lds(
        (const __attribute__((address_space(1))) unsigned int*)src,
        (__attribute__((address_space(3))) unsigned int*)dst, 16, 0, 0);
}
static constexpr size_t XC_BYTES = (size_t)HP * HP * PLANE * 2;       // 11,837,440
static constexpr size_t CO_BYTES = (size_t)1024 * COUT * NBK * 2;     // 20,971,520

// ---- hz ----
__global__ __launch_bounds__(256) void hz_kernel(short* __restrict__ xc)
{
    const int id = blockIdx.x;
    int h, w;
    if (id < 34)      { h = 0;  w = id; }
    else if (id < 68) { h = 33; w = id - 34; }
    else { const int e = id - 68; h = 1 + (e >> 1); w = (e & 1) * 33; }
    uint2* p = reinterpret_cast<uint2*>(xc + (size_t)(h * HP + w) * PLANE);
    const uint2 z = {0u, 0u};
#pragma unroll
    for (int r = 0; r < 5; ++r)
        p[threadIdx.x + r * 256] = z;
}

// ---- t1 (pre-swizzled planes) ----
__global__ __launch_bounds__(256) void t1_kernel(
    const float* __restrict__ x, short* __restrict__ xc)
{
    __shared__ short tile[HW][36];
    const int bid = blockIdx.x;      // 5120 = bk(160) * h(32)
    const int bk  = bid >> 5;
    const int h   = bid & 31;
    const int tid = threadIdx.x;
    {
        const int c  = tid >> 3;
        const int w4 = (tid & 7) * 4;
        const float4 v = *reinterpret_cast<const float4*>(
            x + (size_t)(bk * 32 + c) * 1024 + h * 32 + w4);
        tile[w4 + 0][c] = (short)f2bf(v.x);
        tile[w4 + 1][c] = (short)f2bf(v.y);
        tile[w4 + 2][c] = (short)f2bf(v.z);
        tile[w4 + 3][c] = (short)f2bf(v.w);
    }
    __syncthreads();
    {
        const int w  = tid >> 3;
        const int cq = tid & 7;
        const uint2 pk = *reinterpret_cast<const uint2*>(&tile[w][cq * 4]);
        const int sidx = bk * 32 + ((cq * 4) ^ (((bk >> 1) & 3) << 3));
        *reinterpret_cast<uint2*>(
            xc + (size_t)((h + 1) * HP + (w + 1)) * PLANE + sidx) = pk;
    }
}

// ---- main: (pixel, bk-fifth) blocks, 2 blocks/CU ----
__global__ __launch_bounds__(256) void local2d_s_kernel(
    const short* __restrict__ xc,
    const float* __restrict__ w,
    short* __restrict__ co)
{
    __shared__ short Sl[WOFF3 + COUT * FPAD2];   // 27904 shorts = 55808 B

    const int hb  = blockIdx.x;          // 5120
    const int xcd = hb & 7;              // HW round-robin XCD class
    const int t   = hb >> 3;             // 0..639
    const int q   = t / 5;
    const int sl  = t - q * 5;           // bk-slice 0..4
    const int pp  = xcd * 128 + q;       // pixel 0..1023 (5 slices same XCD)
    const int i   = pp >> 5;
    const int j   = pp & 31;
    const int pix = i * 32 + j;
    const int tid = threadIdx.x;

    const int nt   = tid >> 6;           // wave = N-tile
    const int lane = tid & 63;
    const int l15  = lane & 15;
    const int lg   = lane >> 4;
    const int lg8  = lg * 8;

    // ---- A stage: 9 planes x 128 chunks (16B), this bk-slice only ----
#pragma unroll
    for (int r = 0; r < 5; ++r) {
        const int u = tid + r * 256;
        if (u < 1152) {
            const int pl = u >> 7;               // plane = kw*3 + kh
            const int cu = u & 127;
            const int kw = pl / 3;
            const int kh = pl - kw * 3;
            const short* src = xc + (size_t)((i + kh) * HP + (j + kw)) * PLANE
                                  + sl * SPL + cu * 8;
            gl_lds16(src, Sl + pl * SPL + cu * 8);
        }
    }

    // ---- W: 18 float4/thread -> convert -> LDS [o][cell*32+c], FPAD2 ----
    const float* wp = w + (size_t)pix * (COUT * FDIM);
    float4 wv[18];
#pragma unroll
    for (int qq = 0; qq < 18; ++qq) {
        const int g  = tid + qq * 256;
        const int o2 = g / 72;
        const int f4 = (g - o2 * 72) * 4;
        wv[qq] = *reinterpret_cast<const float4*>(wp + o2 * FDIM + f4);
    }
    short* WL = Sl + WOFF3;
#pragma unroll
    for (int qq = 0; qq < 18; ++qq) {
        const int g  = tid + qq * 256;
        const int o2 = g / 72;
        const int f4 = (g - o2 * 72) * 4;
        const float vv[4] = {wv[qq].x, wv[qq].y, wv[qq].z, wv[qq].w};
        short* wrow = WL + o2 * FPAD2;
#pragma unroll
        for (int e = 0; e < 4; ++e) {
            const int f = f4 + e;
            const int c = f / 9;
            const int cell = f - c * 9;
            wrow[cell * 32 + c] = (short)f2bf(vv[e]);   // max 287 < 292 OK
        }
    }
    __syncthreads();   // compiler drains gl_lds vmcnt + ds writes

    // ---- compute: wave nt; mt in {0,1}; 9 kc ----
    int rowbyte[2];
#pragma unroll
    for (int mt = 0; mt < 2; ++mt) {
        const int bkg = sl * 32 + mt * 16 + l15;   // global bk (swizzle key)
        const int bkl = mt * 16 + l15;             // local row
        rowbyte[mt] = (bkl * 64 + lg * 16) ^ (((bkg >> 1) & 3) << 4);
    }
    const f32x4 z4 = {0.f, 0.f, 0.f, 0.f};
    f32x4 acc0 = z4, acc1 = z4;
    const short* bp = WL + (nt * 16 + l15) * FPAD2 + lg8;

#pragma unroll
    for (int kc = 0; kc < 9; ++kc) {
        const int kh = kc / 3;
        const int kw = kc - kh * 3;
        const char* ab = (const char*)Sl + (kw * 3 + kh) * (SPL * 2);
        const bf16x8 b  = *reinterpret_cast<const bf16x8*>(bp + kc * 32);
        const bf16x8 a0 = *reinterpret_cast<const bf16x8*>(ab + rowbyte[0]);
        const bf16x8 a1 = *reinterpret_cast<const bf16x8*>(ab + rowbyte[1]);
        acc0 = __builtin_amdgcn_mfma_f32_16x16x32_bf16(a0, b, acc0, 0, 0, 0);
        acc1 = __builtin_amdgcn_mfma_f32_16x16x32_bf16(a1, b, acc1, 0, 0, 0);
    }

    // ---- store: co[pix][o][bk] bf16 ----
    {
        const int o3 = nt * 16 + l15;
        const size_t cb = ((size_t)pix * COUT + o3) * NBK + sl * 32 + lg * 4;
#define ST1(a, mt) { s16x4 s_;                                             \
        s_.x = (short)f2bf(a[0]); s_.y = (short)f2bf(a[1]);                \
        s_.z = (short)f2bf(a[2]); s_.w = (short)f2bf(a[3]);                \
        *reinterpret_cast<s16x4*>(co + cb + (mt) * 16) = s_; }
        ST1(acc0, 0) ST1(acc1, 1)
#undef ST1
    }
}

// ---- t2 ----
__global__ __launch_bounds__(256) void t2_kernel(
    const short* __restrict__ co,
    const float* __restrict__ bias,
    float* __restrict__ out)
{
    __shared__ short tl[32][36];
    const int b    = blockIdx.x;          // 10240 = o(64) * bkT(5) * pixT(32)
    const int o    = b & 63;
    const int rest = b >> 6;
    const int bkT  = rest % 5;
    const int pixT = rest / 5;
    const int tid  = threadIdx.x;
    {
        const int p  = tid >> 3;
        const int bq = tid & 7;
        const int pix = pixT * 32 + p;
        const s16x4 v = *reinterpret_cast<const s16x4*>(
            co + ((size_t)pix * COUT + o) * NBK + bkT * 32 + bq * 4);
        *reinterpret_cast<s16x4*>(&tl[p][bq * 4]) = v;
    }
    __syncthreads();
    {
        const int bb = tid >> 3;
        const int pq = tid & 7;
        const int bk = bkT * 32 + bb;
        const int k  = bk % 10;
        const size_t pbase = (size_t)pixT * 32 + pq * 4;
        const float4 bv = *reinterpret_cast<const float4*>(
            bias + ((size_t)(k * COUT + o) << 10) + pbase);
        float4 r;
        r.x = bf2f(tl[pq * 4 + 0][bb]) + bv.x;
        r.y = bf2f(tl[pq * 4 + 1][bb]) + bv.y;
        r.z = bf2f(tl[pq * 4 + 2][bb]) + bv.z;
        r.w = bf2f(tl[pq * 4 + 3][bb]) + bv.w;
        *reinterpret_cast<float4*>(out + ((size_t)(bk * COUT + o) << 10) + pbase) = r;
    }
}

// ================= R3 fallback (proven; needs 10 MB ws) =================
__global__ __launch_bounds__(256) void xpose_kernel(
    const float* __restrict__ x, short* __restrict__ xc)
{
    __shared__ short tile[HW][36];
    const int bid = blockIdx.x;
    const int bk  = bid >> 5;
    const int h   = bid & 31;
    const int tid = threadIdx.x;
    {
        const int c  = tid >> 3;
        const int w4 = (tid & 7) * 4;
        const float4 v = *reinterpret_cast<const float4*>(
            x + (size_t)(bk * 32 + c) * 1024 + h * 32 + w4);
        tile[w4 + 0][c] = (short)f2bf(v.x);
        tile[w4 + 1][c] = (short)f2bf(v.y);
        tile[w4 + 2][c] = (short)f2bf(v.z);
        tile[w4 + 3][c] = (short)f2bf(v.w);
    }
    __syncthreads();
    {
        const int w  = tid >> 3;
        const int cq = tid & 7;
        const uint2 pk = *reinterpret_cast<const uint2*>(&tile[w][cq * 4]);
        *reinterpret_cast<uint2*>(
            xc + ((size_t)(bk * 1024 + h * 32 + w) * 32 + cq * 4)) = pk;
    }
}

__global__ __launch_bounds__(512, 4) void local2d_mfma2_kernel(
    const short* __restrict__ xc,
    const float* __restrict__ w,
    const float* __restrict__ bias,
    float* __restrict__ out)
{
    __shared__ short Wl[COUT * FPAD];
    const int hb  = blockIdx.x;
    const int lb  = (hb & 7) * 128 + (hb >> 3);
    const int i   = lb >> 5;
    const int j   = lb & 31;
    const int pix = i * HW + j;
    const int tid = threadIdx.x;
    {
        const float* wp = w + (size_t)pix * (COUT * FDIM);
#pragma unroll
        for (int p = 0; p < 9; ++p) {
            const int g  = tid + p * 512;
            const int o  = g / 72;
            const int f4 = (g - o * 72) * 4;
            const float4 v = *reinterpret_cast<const float4*>(wp + o * FDIM + f4);
            const float vv[4] = {v.x, v.y, v.z, v.w};
            short* wrow = &Wl[o * FPAD];
#pragma unroll
            for (int e = 0; e < 4; ++e) {
                const int f    = f4 + e;
                const int c    = f / 9;
                const int cell = f - c * 9;
                wrow[cell * 32 + c] = (short)f2bf(vv[e]);
            }
        }
    }
    __syncthreads();
    const int wave = tid >> 6;
    const int lane = tid & 63;
    const int nt   = wave & 3;
    const int mh   = wave >> 2;
    const int l15  = lane & 15;
    const int lg8  = (lane >> 4) * 8;
    f32x4 acc[5];
#pragma unroll
    for (int mt = 0; mt < 5; ++mt)
#pragma unroll
        for (int r = 0; r < 4; ++r) acc[mt][r] = 0.f;
    const short* xb[5];
#pragma unroll
    for (int mt = 0; mt < 5; ++mt) {
        const int bk = mh * 80 + mt * 16 + l15;
        xb[mt] = xc + (size_t)bk * (HW * HW * CIN) + lg8;
    }
    const short* bp = &Wl[(nt * 16 + l15) * FPAD + lg8];
#pragma unroll
    for (int kc = 0; kc < 9; ++kc) {
        const int kh = kc / 3;
        const int kw = kc - kh * 3;
        const int ih = i - 1 + kh;
        const int jw = j - 1 + kw;
        if ((unsigned)ih >= (unsigned)HW || (unsigned)jw >= (unsigned)HW)
            continue;
        const bf16x8 b = *reinterpret_cast<const bf16x8*>(bp + kc * 32);
        const int xoff = (ih * HW + jw) * CIN;
#pragma unroll
        for (int mt = 0; mt < 5; ++mt) {
            const bf16x8 a = *reinterpret_cast<const bf16x8*>(xb[mt] + xoff);
            acc[mt] = __builtin_amdgcn_mfma_f32_16x16x32_bf16(a, b, acc[mt], 0, 0, 0);
        }
    }
    const int o  = nt * 16 + l15;
    const int r0 = (lane >> 4) * 4;
#pragma unroll
    for (int mt = 0; mt < 5; ++mt) {
        const int bk0 = mh * 80 + mt * 16 + r0;
#pragma unroll
        for (int r = 0; r < 4; ++r) {
            const int bk = bk0 + r;
            const int k  = bk % 10;
            out[((size_t)(bk * COUT + o) << 10) + pix] =
                acc[mt][r] + bias[((size_t)(k * COUT + o) << 10) + pix];
        }
    }
}

extern "C" void kernel_launch(void* const* d_in, const int* in_sizes, int n_in,
                              void* d_out, int out_size, void* d_ws, size_t ws_size,
                              hipStream_t stream) {
    const float* x    = (const float*)d_in[0];
    const float* w    = (const float*)d_in[1];
    const float* bias = (const float*)d_in[2];
    float* out        = (float*)d_out;

    if (ws_size >= XC_BYTES + CO_BYTES) {
        short* xc = (short*)d_ws;
        short* co = (short*)((char*)d_ws + XC_BYTES);
        hipLaunchKernelGGL(hz_kernel, dim3(132), dim3(256), 0, stream, xc);
        hipLaunchKernelGGL(t1_kernel, dim3(5120), dim3(256), 0, stream, x, xc);
        hipLaunchKernelGGL(local2d_s_kernel, dim3(5120), dim3(256), 0, stream,
                           xc, w, co);
        hipLaunchKernelGGL(t2_kernel, dim3(10240), dim3(256), 0, stream,
                           co, bias, out);
    } else {
        short* xc = (short*)d_ws;
        hipLaunchKernelGGL(xpose_kernel, dim3(5120), dim3(256), 0, stream, x, xc);
        hipLaunchKernelGGL(local2d_mfma2_kernel, dim3(1024), dim3(512), 0, stream,
                           xc, w, bias, out);
    }
}

// Round 17
// 63.647 us; speedup vs baseline: 1.3988x; 1.3988x over previous
//
#include <hip/hip_runtime.h>

// VecLocal2d R17: W fragment-pack pre-pass (t3 -> d_out-as-scratch) + main
// kernel with ZERO W-reorder VALU (pure gl_lds copies) + 2 blocks/CU.
// R16 isolated the W-scatter as first-order cost (47% VALUBusy at 5x);
// R17 does the reorder once (t3, streaming) and stages it by linear copy.
//   hz:  zero halo planes of xc
//   t1:  x -> xc[(h+1)][(w+1)][bk][c] bf16, planes pre-XOR-swizzled (R9)
//   t3:  w[pix][o][f] fp32 -> wpack[pix][kc][nt][lane][8] bf16 (R13, proven)
//        wpack lives in d_out (41.9MB >= 37.7MB); t2 overwrites it later.
//   mz:  block = (pixel, 64-bk slice): A 9 planes x 64 rows (36864B) +
//        W copy (36864B) = 73728B LDS -> 2 blocks/CU. One barrier.
//        B-frag ds_reads lane*16B contiguous (conflict-free); A XOR-swz.
//        3 slices/pixel share an XCD (W re-reads are L2 hits).
//   t2:  out[bk][o][pix] = f32(co) + bias  (proven)
// Fallback (ws < 32.8 MB): R3 path (proven, 10 MB).

#define HW    32
#define CIN   32
#define COUT  64
#define FDIM  288
#define FPAD  296              // t3/fallback W-LDS pad
#define NBK   160
#define HP    34
#define PLANE 5120             // xc plane shorts (160 bk x 32 c)
#define SPL64 2048             // 64-row slice shorts per plane
#define WOFF4 (9 * SPL64)      // 18432 shorts: W region start in mz LDS
#define WPK   18432            // shorts per pixel in wpack (9*4*64*8)

using f32x4  = __attribute__((ext_vector_type(4))) float;
using bf16x8 = __attribute__((ext_vector_type(8))) short;
using s16x4  = __attribute__((ext_vector_type(4))) short;

static __device__ inline unsigned short f2bf(float f) {
    unsigned u = __float_as_uint(f);
    u += 0x7FFFu + ((u >> 16) & 1u);   // round-to-nearest-even
    return (unsigned short)(u >> 16);
}
static __device__ inline float bf2f(short h) {
    return __uint_as_float(((unsigned)(unsigned short)h) << 16);
}
static __device__ inline void gl_lds16(const short* src, short* dst) {
    __builtin_amdgcn_global_load_lds(
        (const __attribute__((address_space(1))) unsigned int*)src,
        (__attribute__((address_space(3))) unsigned int*)dst, 16, 0, 0);
}
static constexpr size_t XC_BYTES = (size_t)HP * HP * PLANE * 2;       // 11,837,440
static constexpr size_t CO_BYTES = (size_t)1024 * COUT * NBK * 2;     // 20,971,520

// ---- hz ----
__global__ __launch_bounds__(256) void hz_kernel(short* __restrict__ xc)
{
    const int id = blockIdx.x;
    int h, w;
    if (id < 34)      { h = 0;  w = id; }
    else if (id < 68) { h = 33; w = id - 34; }
    else { const int e = id - 68; h = 1 + (e >> 1); w = (e & 1) * 33; }
    uint2* p = reinterpret_cast<uint2*>(xc + (size_t)(h * HP + w) * PLANE);
    const uint2 z = {0u, 0u};
#pragma unroll
    for (int r = 0; r < 5; ++r)
        p[threadIdx.x + r * 256] = z;
}

// ---- t1 (pre-swizzled planes, R9) ----
__global__ __launch_bounds__(256) void t1_kernel(
    const float* __restrict__ x, short* __restrict__ xc)
{
    __shared__ short tile[HW][36];
    const int bid = blockIdx.x;      // 5120 = bk(160) * h(32)
    const int bk  = bid >> 5;
    const int h   = bid & 31;
    const int tid = threadIdx.x;
    {
        const int c  = tid >> 3;
        const int w4 = (tid & 7) * 4;
        const float4 v = *reinterpret_cast<const float4*>(
            x + (size_t)(bk * 32 + c) * 1024 + h * 32 + w4);
        tile[w4 + 0][c] = (short)f2bf(v.x);
        tile[w4 + 1][c] = (short)f2bf(v.y);
        tile[w4 + 2][c] = (short)f2bf(v.z);
        tile[w4 + 3][c] = (short)f2bf(v.w);
    }
    __syncthreads();
    {
        const int w  = tid >> 3;
        const int cq = tid & 7;
        const uint2 pk = *reinterpret_cast<const uint2*>(&tile[w][cq * 4]);
        const int sidx = bk * 32 + ((cq * 4) ^ (((bk >> 1) & 3) << 3));
        *reinterpret_cast<uint2*>(
            xc + (size_t)((h + 1) * HP + (w + 1)) * PLANE + sidx) = pk;
    }
}

// ---- t3: w -> wpack (MFMA fragment layout; R13, proven) ----
__global__ __launch_bounds__(256) void t3_kernel(
    const float* __restrict__ w, short* __restrict__ wpack)
{
    __shared__ short Wl[COUT * FPAD];   // [o][cell*32 + c]
    const int pix = blockIdx.x;
    const int tid = threadIdx.x;
    {
        const float* wp = w + (size_t)pix * (COUT * FDIM);
#pragma unroll
        for (int q = 0; q < 18; ++q) {
            const int g  = tid + q * 256;
            const int o  = g / 72;
            const int f4 = (g - o * 72) * 4;
            const float4 v = *reinterpret_cast<const float4*>(wp + o * FDIM + f4);
            const float vv[4] = {v.x, v.y, v.z, v.w};
            short* wrow = &Wl[o * FPAD];
#pragma unroll
            for (int e = 0; e < 4; ++e) {
                const int f = f4 + e;
                const int c = f / 9;
                const int cell = f - c * 9;
                wrow[cell * 32 + c] = (short)f2bf(vv[e]);
            }
        }
    }
    __syncthreads();
    {
        short* dst = wpack + (size_t)pix * WPK;
#pragma unroll
        for (int q = 0; q < 9; ++q) {
            const int u    = tid + q * 256;
            const int kc   = u >> 8;
            const int rem  = u & 255;
            const int nt   = rem >> 6;
            const int lane = rem & 63;
            const int l15  = lane & 15;
            const int lg   = lane >> 4;
            const s16x4* src = reinterpret_cast<const s16x4*>(
                &Wl[(nt * 16 + l15) * FPAD + kc * 32 + lg * 8]);
            *reinterpret_cast<s16x4*>(dst + (size_t)u * 8 + 0) = src[0];
            *reinterpret_cast<s16x4*>(dst + (size_t)u * 8 + 4) = src[1];
        }
    }
}

// ---- mz: (pixel, 64-bk slice) blocks; pure-copy staging; 2 blocks/CU ----
__global__ __launch_bounds__(256) void local2d_z_kernel(
    const short* __restrict__ xc,
    const short* __restrict__ wpack,
    short* __restrict__ co)
{
    __shared__ short Sl[WOFF4 + WPK];    // 36864 shorts = 73728 B

    const int hb  = blockIdx.x;          // 3072 = 8 xcd * 384
    const int xcd = hb & 7;
    const int t   = hb >> 3;             // 0..383
    const int q   = t / 3;
    const int sl  = t - q * 3;           // slice 0..2
    const int pp  = xcd * 128 + q;       // pixel; 3 slices share an XCD
    const int i   = pp >> 5;
    const int j   = pp & 31;
    const int pix = i * 32 + j;
    const int bk0 = sl * 64;
    const int nch = (sl < 2) ? 256 : 128;   // 16B chunks per A plane
    const int tid = threadIdx.x;

    // ---- A stage: 9 planes x nch chunks, contiguous slice copy ----
#pragma unroll
    for (int r = 0; r < 9; ++r) {
        const int u  = tid + r * 256;       // 0..2303
        const int pl = u >> 8;              // plane = kw*3 + kh
        const int cu = u & 255;
        if (cu < nch) {
            const int kw = pl / 3;
            const int kh = pl - kw * 3;
            const short* src = xc + (size_t)((i + kh) * HP + (j + kw)) * PLANE
                                  + bk0 * 32 + cu * 8;
            gl_lds16(src, Sl + pl * SPL64 + cu * 8);
        }
    }
    // ---- W stage: pure linear copy of wpack[pix] (2304 chunks) ----
    {
        const short* wpg = wpack + (size_t)pix * WPK;
#pragma unroll
        for (int r = 0; r < 9; ++r) {
            const int u = tid + r * 256;
            gl_lds16(wpg + (size_t)u * 8, Sl + WOFF4 + (size_t)u * 8);
        }
    }
    __syncthreads();    // compiler drains vmcnt; co-resident block overlaps

    // ---- compute: wave = nt; mt 0..3 (upper 2 unstored for sl==2) ----
    const int nt   = tid >> 6;
    const int lane = tid & 63;
    const int l15  = lane & 15;
    const int lg   = lane >> 4;

    int rowbyte[4];
#pragma unroll
    for (int mt = 0; mt < 4; ++mt) {
        const int bkl = mt * 16 + l15;       // slice-local; swz key invariant
        rowbyte[mt] = (bkl * 64 + lg * 16) ^ (((bkl >> 1) & 3) << 4);
    }
    const f32x4 z4 = {0.f, 0.f, 0.f, 0.f};
    f32x4 acc0 = z4, acc1 = z4, acc2 = z4, acc3 = z4;
    const short* WL = Sl + WOFF4;

#pragma unroll
    for (int kc = 0; kc < 9; ++kc) {
        const int kh = kc / 3;
        const int kw = kc - kh * 3;
        const char* ab = (const char*)Sl + (kw * 3 + kh) * (SPL64 * 2);
        const bf16x8 b  = *reinterpret_cast<const bf16x8*>(
            WL + (kc * 4 + nt) * 512 + lane * 8);          // lane*16B: conflict-free
        const bf16x8 a0 = *reinterpret_cast<const bf16x8*>(ab + rowbyte[0]);
        const bf16x8 a1 = *reinterpret_cast<const bf16x8*>(ab + rowbyte[1]);
        const bf16x8 a2 = *reinterpret_cast<const bf16x8*>(ab + rowbyte[2]);
        const bf16x8 a3 = *reinterpret_cast<const bf16x8*>(ab + rowbyte[3]);
        acc0 = __builtin_amdgcn_mfma_f32_16x16x32_bf16(a0, b, acc0, 0, 0, 0);
        acc1 = __builtin_amdgcn_mfma_f32_16x16x32_bf16(a1, b, acc1, 0, 0, 0);
        acc2 = __builtin_amdgcn_mfma_f32_16x16x32_bf16(a2, b, acc2, 0, 0, 0);
        acc3 = __builtin_amdgcn_mfma_f32_16x16x32_bf16(a3, b, acc3, 0, 0, 0);
    }

    // ---- store: co[pix][o][bk] bf16 (partial slice stores mt 0,1 only) ----
    {
        const int o3 = nt * 16 + l15;
        const size_t cb = ((size_t)pix * COUT + o3) * NBK + bk0 + lg * 4;
#define ST1(a, mt) { s16x4 s_;                                             \
        s_.x = (short)f2bf(a[0]); s_.y = (short)f2bf(a[1]);                \
        s_.z = (short)f2bf(a[2]); s_.w = (short)f2bf(a[3]);                \
        *reinterpret_cast<s16x4*>(co + cb + (mt) * 16) = s_; }
        ST1(acc0, 0) ST1(acc1, 1)
        if (sl < 2) { ST1(acc2, 2) ST1(acc3, 3) }
#undef ST1
    }
}

// ---- t2 ----
__global__ __launch_bounds__(256) void t2_kernel(
    const short* __restrict__ co,
    const float* __restrict__ bias,
    float* __restrict__ out)
{
    __shared__ short tl[32][36];
    const int b    = blockIdx.x;          // 10240 = o(64) * bkT(5) * pixT(32)
    const int o    = b & 63;
    const int rest = b >> 6;
    const int bkT  = rest % 5;
    const int pixT = rest / 5;
    const int tid  = threadIdx.x;
    {
        const int p  = tid >> 3;
        const int bq = tid & 7;
        const int pix = pixT * 32 + p;
        const s16x4 v = *reinterpret_cast<const s16x4*>(
            co + ((size_t)pix * COUT + o) * NBK + bkT * 32 + bq * 4);
        *reinterpret_cast<s16x4*>(&tl[p][bq * 4]) = v;
    }
    __syncthreads();
    {
        const int bb = tid >> 3;
        const int pq = tid & 7;
        const int bk = bkT * 32 + bb;
        const int k  = bk % 10;
        const size_t pbase = (size_t)pixT * 32 + pq * 4;
        const float4 bv = *reinterpret_cast<const float4*>(
            bias + ((size_t)(k * COUT + o) << 10) + pbase);
        float4 r;
        r.x = bf2f(tl[pq * 4 + 0][bb]) + bv.x;
        r.y = bf2f(tl[pq * 4 + 1][bb]) + bv.y;
        r.z = bf2f(tl[pq * 4 + 2][bb]) + bv.z;
        r.w = bf2f(tl[pq * 4 + 3][bb]) + bv.w;
        *reinterpret_cast<float4*>(out + ((size_t)(bk * COUT + o) << 10) + pbase) = r;
    }
}

// ================= R3 fallback (proven; needs 10 MB ws) =================
__global__ __launch_bounds__(256) void xpose_kernel(
    const float* __restrict__ x, short* __restrict__ xc)
{
    __shared__ short tile[HW][36];
    const int bid = blockIdx.x;
    const int bk  = bid >> 5;
    const int h   = bid & 31;
    const int tid = threadIdx.x;
    {
        const int c  = tid >> 3;
        const int w4 = (tid & 7) * 4;
        const float4 v = *reinterpret_cast<const float4*>(
            x + (size_t)(bk * 32 + c) * 1024 + h * 32 + w4);
        tile[w4 + 0][c] = (short)f2bf(v.x);
        tile[w4 + 1][c] = (short)f2bf(v.y);
        tile[w4 + 2][c] = (short)f2bf(v.z);
        tile[w4 + 3][c] = (short)f2bf(v.w);
    }
    __syncthreads();
    {
        const int w  = tid >> 3;
        const int cq = tid & 7;
        const uint2 pk = *reinterpret_cast<const uint2*>(&tile[w][cq * 4]);
        *reinterpret_cast<uint2*>(
            xc + ((size_t)(bk * 1024 + h * 32 + w) * 32 + cq * 4)) = pk;
    }
}

__global__ __launch_bounds__(512, 4) void local2d_mfma2_kernel(
    const short* __restrict__ xc,
    const float* __restrict__ w,
    const float* __restrict__ bias,
    float* __restrict__ out)
{
    __shared__ short Wl[COUT * FPAD];
    const int hb  = blockIdx.x;
    const int lb  = (hb & 7) * 128 + (hb >> 3);
    const int i   = lb >> 5;
    const int j   = lb & 31;
    const int pix = i * HW + j;
    const int tid = threadIdx.x;
    {
        const float* wp = w + (size_t)pix * (COUT * FDIM);
#pragma unroll
        for (int p = 0; p < 9; ++p) {
            const int g  = tid + p * 512;
            const int o  = g / 72;
            const int f4 = (g - o * 72) * 4;
            const float4 v = *reinterpret_cast<const float4*>(wp + o * FDIM + f4);
            const float vv[4] = {v.x, v.y, v.z, v.w};
            short* wrow = &Wl[o * FPAD];
#pragma unroll
            for (int e = 0; e < 4; ++e) {
                const int f    = f4 + e;
                const int c    = f / 9;
                const int cell = f - c * 9;
                wrow[cell * 32 + c] = (short)f2bf(vv[e]);
            }
        }
    }
    __syncthreads();
    const int wave = tid >> 6;
    const int lane = tid & 63;
    const int nt   = wave & 3;
    const int mh   = wave >> 2;
    const int l15  = lane & 15;
    const int lg8  = (lane >> 4) * 8;
    f32x4 acc[5];
#pragma unroll
    for (int mt = 0; mt < 5; ++mt)
#pragma unroll
        for (int r = 0; r < 4; ++r) acc[mt][r] = 0.f;
    const short* xb[5];
#pragma unroll
    for (int mt = 0; mt < 5; ++mt) {
        const int bk = mh * 80 + mt * 16 + l15;
        xb[mt] = xc + (size_t)bk * (HW * HW * CIN) + lg8;
    }
    const short* bp = &Wl[(nt * 16 + l15) * FPAD + lg8];
#pragma unroll
    for (int kc = 0; kc < 9; ++kc) {
        const int kh = kc / 3;
        const int kw = kc - kh * 3;
        const int ih = i - 1 + kh;
        const int jw = j - 1 + kw;
        if ((unsigned)ih >= (unsigned)HW || (unsigned)jw >= (unsigned)HW)
            continue;
        const bf16x8 b = *reinterpret_cast<const bf16x8*>(bp + kc * 32);
        const int xoff = (ih * HW + jw) * CIN;
#pragma unroll
        for (int mt = 0; mt < 5; ++mt) {
            const bf16x8 a = *reinterpret_cast<const bf16x8*>(xb[mt] + xoff);
            acc[mt] = __builtin_amdgcn_mfma_f32_16x16x32_bf16(a, b, acc[mt], 0, 0, 0);
        }
    }
    const int o  = nt * 16 + l15;
    const int r0 = (lane >> 4) * 4;
#pragma unroll
    for (int mt = 0; mt < 5; ++mt) {
        const int bk0 = mh * 80 + mt * 16 + r0;
#pragma unroll
        for (int r = 0; r < 4; ++r) {
            const int bk = bk0 + r;
            const int k  = bk % 10;
            out[((size_t)(bk * COUT + o) << 10) + pix] =
                acc[mt][r] + bias[((size_t)(k * COUT + o) << 10) + pix];
        }
    }
}

extern "C" void kernel_launch(void* const* d_in, const int* in_sizes, int n_in,
                              void* d_out, int out_size, void* d_ws, size_t ws_size,
                              hipStream_t stream) {
    const float* x    = (const float*)d_in[0];
    const float* w    = (const float*)d_in[1];
    const float* bias = (const float*)d_in[2];
    float* out        = (float*)d_out;

    if (ws_size >= XC_BYTES + CO_BYTES) {
        short* xc    = (short*)d_ws;
        short* co    = (short*)((char*)d_ws + XC_BYTES);
        short* wpack = (short*)d_out;     // d_out as scratch; t2 overwrites it
        hipLaunchKernelGGL(hz_kernel, dim3(132), dim3(256), 0, stream, xc);
        hipLaunchKernelGGL(t1_kernel, dim3(5120), dim3(256), 0, stream, x, xc);
        hipLaunchKernelGGL(t3_kernel, dim3(1024), dim3(256), 0, stream, w, wpack);
        hipLaunchKernelGGL(local2d_z_kernel, dim3(3072), dim3(256), 0, stream,
                           xc, wpack, co);
        hipLaunchKernelGGL(t2_kernel, dim3(10240), dim3(256), 0, stream,
                           co, bias, out);
    } else {
        short* xc = (short*)d_ws;
        hipLaunchKernelGGL(xpose_kernel, dim3(5120), dim3(256), 0, stream, x, xc);
        hipLaunchKernelGGL(local2d_mfma2_kernel, dim3(1024), dim3(512), 0, stream,
                           xc, w, bias, out);
    }
}